// Round 2
// baseline (38142.294 us; speedup 1.0000x reference)
//
#include <hip/hip_runtime.h>
#include <hip/hip_bf16.h>
#include <math.h>

// ---------------------------------------------------------------------------
// VRNN on MI355X — Round 5: persistent sequential kernel (R4 + ws fix).
// R4 crashed: ws_needed() was stale (missing HH/GXX growth terms), so the
// adaptive TC selection overflowed the workspace and GXX ran off the end.
// ws_needed now walks the exact same offset chain as the layout code.
// Design unchanged: per-batch-row-independent recurrence -> ONE plain kernel
// (32 WGs x 512 thr, WG owns 16 batch rows) runs all TC steps; phi_x
// contributions hoisted into batched pre-GEMMs (E1X, GXX).
// ---------------------------------------------------------------------------

typedef __attribute__((ext_vector_type(8))) short bfrag;   // 8 x bf16
typedef __attribute__((ext_vector_type(4))) float ffrag;   // 4 x f32
typedef __hip_bfloat16 bf16;

__device__ __forceinline__ float softplus_f(float v) {
    return (v > 20.f) ? v : log1pf(expf(v));
}
__device__ __forceinline__ float sigmoid_f(float v) {
    return 1.f / (1.f + expf(-v));
}

// ---- setup converters ----
__global__ __launch_bounds__(256) void f2b_kernel(
    const float* __restrict__ s, bf16* __restrict__ d, int n)
{
    int i = blockIdx.x * 256 + threadIdx.x;
    if (i < n) d[i] = __float2bfloat16(s[i]);
}
__global__ __launch_bounds__(256) void fcopy_kernel(
    const float* __restrict__ s, float* __restrict__ d, int n)
{
    int i = blockIdx.x * 256 + threadIdx.x;
    if (i < n) d[i] = s[i];
}

__global__ __launch_bounds__(256) void init_kernel(
    float* __restrict__ hlive, float* __restrict__ out)
{
    const int idx = blockIdx.x * 256 + threadIdx.x;
    if (idx < 262144) hlive[idx] = 0.f;
    if (idx < 3) out[idx] = 0.f;
}

// ---------------------------------------------------------------------------
// MFMA GEMM: C[M,N] = act(bias + sum_s A_s @ W_s^T)   (unchanged, verified)
// act: 0 none, 1 relu, 2 softplus on col>=32, 3 relu on col<64 only.
// ---------------------------------------------------------------------------
__global__ __launch_bounds__(256) void mfma_gemm(
    const bf16* __restrict__ A0, int lda0, const bf16* __restrict__ W0, int ldw0, int K0,
    const bf16* __restrict__ A1, int lda1, const bf16* __restrict__ W1, int ldw1, int K1,
    const float* __restrict__ bias, int act,
    void* __restrict__ C, int ldc, int obf)
{
    const int tid = threadIdx.x;
    const int L = tid & 63, w = tid >> 6;
    const int m0 = blockIdx.y * 64 + (w & 1) * 32;
    const int n0 = blockIdx.x * 64 + (w >> 1) * 32;
    const int lr = L & 15;
    const int lk = (L >> 4) * 8;

    ffrag acc[2][2];
#pragma unroll
    for (int i = 0; i < 2; ++i)
#pragma unroll
        for (int j = 0; j < 2; ++j)
#pragma unroll
            for (int r = 0; r < 4; ++r) acc[i][j][r] = 0.f;

    for (int s = 0; s < 2; ++s) {
        const bf16* A = s ? A1 : A0;
        if (!A) break;
        const bf16* W = s ? W1 : W0;
        const int lda = s ? lda1 : lda0;
        const int ldw = s ? ldw1 : ldw0;
        const int K   = s ? K1 : K0;
        const bf16* a0p = A + (size_t)(m0 + lr) * lda + lk;
        const bf16* a1p = a0p + (size_t)16 * lda;
        const bf16* b0p = W + (size_t)(n0 + lr) * ldw + lk;
        const bf16* b1p = b0p + (size_t)16 * ldw;
        for (int k0 = 0; k0 < K; k0 += 32) {
            bfrag a0 = *(const bfrag*)(a0p + k0);
            bfrag a1 = *(const bfrag*)(a1p + k0);
            bfrag b0 = *(const bfrag*)(b0p + k0);
            bfrag b1 = *(const bfrag*)(b1p + k0);
            acc[0][0] = __builtin_amdgcn_mfma_f32_16x16x32_bf16(a0, b0, acc[0][0], 0, 0, 0);
            acc[0][1] = __builtin_amdgcn_mfma_f32_16x16x32_bf16(a0, b1, acc[0][1], 0, 0, 0);
            acc[1][0] = __builtin_amdgcn_mfma_f32_16x16x32_bf16(a1, b0, acc[1][0], 0, 0, 0);
            acc[1][1] = __builtin_amdgcn_mfma_f32_16x16x32_bf16(a1, b1, acc[1][1], 0, 0, 0);
        }
    }

#pragma unroll
    for (int i = 0; i < 2; ++i)
#pragma unroll
    for (int j = 0; j < 2; ++j)
#pragma unroll
    for (int r = 0; r < 4; ++r) {
        const int row = m0 + 16 * i + (L >> 4) * 4 + r;
        const int col = n0 + 16 * j + lr;
        float v = acc[i][j][r];
        if (bias) v += bias[col];
        if (act == 1) v = fmaxf(v, 0.f);
        else if (act == 2) { if (col >= 32) v = softplus_f(v); }
        else if (act == 3) { if (col < 64) v = fmaxf(v, 0.f); }
        const size_t g = (size_t)row * ldc + col;
        if (obf) ((bf16*)C)[g] = __float2bfloat16(v);
        else     ((float*)C)[g] = v;
    }
}

// ---------------------------------------------------------------------------
// Persistent sequential kernel. Grid 32 x 512 thr (8 waves). WG g owns batch
// rows [16g, 16g+16) for ALL TC steps. Per step, per wave w (cols 64w..+64):
//   A: p1 = relu(E1X[t] + h @ eW1h^T)           (LDS bf16)
//   B: p2 = relu(p1 @ eW2^T + eb2)
//   C: ms = p2 @ msw^T + msb (softplus hi), EMSC out; z; p1 = relu(z@pzw^T+b)
//   D: gates = GXX[t] + p1 @ Wihz^T , h @ Whh^T; h_new -> HLIVE (fp32) +
//      HH[t+1]; then hB refreshed from HLIVE.
// LDS tiles padded to stride 536 (1072 B). Static LDS = 56.9 KB.
// ---------------------------------------------------------------------------
#define AST 536

__global__ __launch_bounds__(512, 1) void seq_kernel(
    const bf16* __restrict__ e1x,     // [TC*512,512] phi_x@eW1x^T + eb1
    const bf16* __restrict__ gxx,     // [TC*512,1536] phi_x@Wihx^T
    const float* __restrict__ eps_c,  // [TC*512,32]
    const bf16* __restrict__ ew1h,    // row n at +n*1024, K=512 (h-cols of eW1)
    const bf16* __restrict__ ew2,     // [512,512]
    const float* __restrict__ eb2,
    const bf16* __restrict__ msw,     // [64,512]
    const float* __restrict__ msb,    // [64] (emb|esb)
    const bf16* __restrict__ pzw,     // [512,32]
    const float* __restrict__ pzb,    // [512]
    const bf16* __restrict__ wihz,    // row n at +n*1024, K=512 (z-cols of Wih)
    const bf16* __restrict__ whh,     // [1536,512]
    float* __restrict__ hlive,        // [512,512] fp32 h (in/out)
    bf16* __restrict__ hh,            // [(TC+1)*512,512] history
    float* __restrict__ emsc,         // [TC*512,64]
    bf16* __restrict__ phizc,         // [TC*512,512]
    int TC)
{
    __shared__ __align__(16) bf16 hB[16][AST];
    __shared__ __align__(16) bf16 p1[16][AST];
    __shared__ __align__(16) bf16 p2[16][AST];
    __shared__ float msd[16][65];
    __shared__ __align__(16) bf16 zb[16][40];

    const int tid = threadIdx.x;
    const int L = tid & 63, w = tid >> 6;       // w in 0..7
    const int lr = L & 15, lk = (L >> 4) * 8;
    const int rq = (L >> 4) * 4;                // C-fragment row base
    const int m0 = blockIdx.x * 16;             // global batch-row base

    // ---- load h (fp32 from HLIVE), publish bf16 copy + history slot 0 ----
    for (int i = tid; i < 8192; i += 512) {
        const int r = i >> 9, c = i & 511;
        const float v = hlive[(size_t)(m0 + r) * 512 + c];
        const bf16 bv = __float2bfloat16(v);
        hB[r][c] = bv;
        hh[(size_t)(m0 + r) * 512 + c] = bv;
    }
    __syncthreads();

    for (int lt = 0; lt < TC; ++lt) {
        const size_t rb = (size_t)lt * 512 + m0;

        // ---------- stage A: p1 = relu(E1X + h @ eW1h^T) ----------
        {
            ffrag acc[4];
#pragma unroll
            for (int nt = 0; nt < 4; ++nt)
#pragma unroll
                for (int r = 0; r < 4; ++r) acc[nt][r] = 0.f;
#pragma unroll 4
            for (int k0 = 0; k0 < 512; k0 += 32) {
                bfrag a = *(const bfrag*)&hB[lr][k0 + lk];
#pragma unroll
                for (int nt = 0; nt < 4; ++nt) {
                    const int col = 64 * w + 16 * nt + lr;
                    bfrag b = *(const bfrag*)(ew1h + (size_t)col * 1024 + k0 + lk);
                    acc[nt] = __builtin_amdgcn_mfma_f32_16x16x32_bf16(a, b, acc[nt], 0, 0, 0);
                }
            }
#pragma unroll
            for (int nt = 0; nt < 4; ++nt)
#pragma unroll
            for (int r = 0; r < 4; ++r) {
                const int row = rq + r, col = 64 * w + 16 * nt + lr;
                float v = acc[nt][r] + __bfloat162float(e1x[(rb + row) * 512 + col]);
                p1[row][col] = __float2bfloat16(fmaxf(v, 0.f));
            }
        }
        __syncthreads();

        // ---------- stage B: p2 = relu(p1 @ eW2^T + eb2) ----------
        {
            ffrag acc[4];
#pragma unroll
            for (int nt = 0; nt < 4; ++nt)
#pragma unroll
                for (int r = 0; r < 4; ++r) acc[nt][r] = 0.f;
#pragma unroll 4
            for (int k0 = 0; k0 < 512; k0 += 32) {
                bfrag a = *(const bfrag*)&p1[lr][k0 + lk];
#pragma unroll
                for (int nt = 0; nt < 4; ++nt) {
                    const int col = 64 * w + 16 * nt + lr;
                    bfrag b = *(const bfrag*)(ew2 + (size_t)col * 512 + k0 + lk);
                    acc[nt] = __builtin_amdgcn_mfma_f32_16x16x32_bf16(a, b, acc[nt], 0, 0, 0);
                }
            }
#pragma unroll
            for (int nt = 0; nt < 4; ++nt)
#pragma unroll
            for (int r = 0; r < 4; ++r) {
                const int row = rq + r, col = 64 * w + 16 * nt + lr;
                float v = fmaxf(acc[nt][r] + eb2[col], 0.f);
                p2[row][col] = __float2bfloat16(v);
            }
        }
        __syncthreads();

        // ---------- stage C1: ms = p2 @ msw^T + msb (softplus cols>=32) ----
        if (w < 4) {
            ffrag acc;
#pragma unroll
            for (int r = 0; r < 4; ++r) acc[r] = 0.f;
#pragma unroll 4
            for (int k0 = 0; k0 < 512; k0 += 32) {
                bfrag a = *(const bfrag*)&p2[lr][k0 + lk];
                bfrag b = *(const bfrag*)(msw + (size_t)(16 * w + lr) * 512 + k0 + lk);
                acc = __builtin_amdgcn_mfma_f32_16x16x32_bf16(a, b, acc, 0, 0, 0);
            }
#pragma unroll
            for (int r = 0; r < 4; ++r) {
                const int row = rq + r, col = 16 * w + lr;
                float v = acc[r] + msb[col];
                if (col >= 32) v = softplus_f(v);
                msd[row][col] = v;
                emsc[(rb + row) * 64 + col] = v;
            }
        }
        __syncthreads();

        // ---------- stage C2: z = eps*std + mean (x10 on cols<4) ----------
        {
            const int row = tid >> 5, c = tid & 31;
            float zv = eps_c[(rb + row) * 32 + c] * msd[row][32 + c] + msd[row][c];
            if (c < 4) zv *= 10.f;
            zb[row][c] = __float2bfloat16(zv);
        }
        __syncthreads();

        // ---------- stage C3: p1 = relu(z @ pzw^T + pzb) (+ PHIZC) --------
        {
            bfrag a = *(const bfrag*)&zb[lr][lk];
#pragma unroll
            for (int nt = 0; nt < 4; ++nt) {
                const int col = 64 * w + 16 * nt + lr;
                bfrag b = *(const bfrag*)(pzw + (size_t)col * 32 + lk);
                ffrag c_;
#pragma unroll
                for (int r = 0; r < 4; ++r) c_[r] = 0.f;
                c_ = __builtin_amdgcn_mfma_f32_16x16x32_bf16(a, b, c_, 0, 0, 0);
#pragma unroll
                for (int r = 0; r < 4; ++r) {
                    const int row = rq + r;
                    const float v = fmaxf(c_[r] + pzb[col], 0.f);
                    const bf16 bv = __float2bfloat16(v);
                    p1[row][col] = bv;
                    phizc[(rb + row) * 512 + col] = bv;
                }
            }
        }
        __syncthreads();

        // ---------- stage D: GRU ----------
        {
            bf16* hnext = hh + (size_t)(lt + 1) * 262144;
            for (int nt = 0; nt < 4; ++nt) {
                const int col = 64 * w + 16 * nt + lr;
                ffrag az[3], ah[3];
#pragma unroll
                for (int g = 0; g < 3; ++g)
#pragma unroll
                    for (int r = 0; r < 4; ++r) { az[g][r] = 0.f; ah[g][r] = 0.f; }
#pragma unroll 2
                for (int k0 = 0; k0 < 512; k0 += 32) {
                    bfrag aZ = *(const bfrag*)&p1[lr][k0 + lk];
                    bfrag aH = *(const bfrag*)&hB[lr][k0 + lk];
#pragma unroll
                    for (int g = 0; g < 3; ++g) {
                        const size_t wr = (size_t)(col + 512 * g);
                        bfrag bZ = *(const bfrag*)(wihz + wr * 1024 + k0 + lk);
                        bfrag bH = *(const bfrag*)(whh + wr * 512 + k0 + lk);
                        az[g] = __builtin_amdgcn_mfma_f32_16x16x32_bf16(aZ, bZ, az[g], 0, 0, 0);
                        ah[g] = __builtin_amdgcn_mfma_f32_16x16x32_bf16(aH, bH, ah[g], 0, 0, 0);
                    }
                }
#pragma unroll
                for (int r = 0; r < 4; ++r) {
                    const int row = rq + r;
                    const size_t gb = (rb + row) * 1536 + col;
                    const float xr = __bfloat162float(gxx[gb]) + az[0][r];
                    const float xz = __bfloat162float(gxx[gb + 512]) + az[1][r];
                    const float xn = __bfloat162float(gxx[gb + 1024]) + az[2][r];
                    const float rg = sigmoid_f(xr + ah[0][r]);
                    const float zg = sigmoid_f(xz + ah[1][r]);
                    const float nv = tanhf(xn + rg * ah[2][r]);
                    const size_t gidx = (size_t)(m0 + row) * 512 + col;
                    const float hv = hlive[gidx];
                    const float hnew = (1.f - zg) * nv + zg * hv;
                    hlive[gidx] = hnew;              // own cols only: no race
                    hnext[gidx] = __float2bfloat16(hnew);
                }
            }
        }
        __syncthreads();   // all waves done reading hB/p1; hlive writes visible

        // ---------- refresh bf16 h for next step ----------
        for (int i = tid; i < 8192; i += 512) {
            const int r = i >> 9, c = i & 511;
            hB[r][c] = __float2bfloat16(hlive[(size_t)(m0 + r) * 512 + c]);
        }
        __syncthreads();
    }
}

// ---------------------------------------------------------------------------
// KLD: emsc [M,64] = (enc_mean | enc_std), pms same for prior. (unchanged)
// ---------------------------------------------------------------------------
__global__ __launch_bounds__(256) void kld_kernel(
    const float* __restrict__ emsc, const float* __restrict__ pms,
    float* __restrict__ out)
{
    const size_t p0 = (size_t)blockIdx.x * 1024 + threadIdx.x;
    float acc = 0.f;
#pragma unroll
    for (int rep = 0; rep < 4; ++rep) {
        const size_t p = p0 + (size_t)rep * 256;
        const size_t i = p >> 5; const int c = p & 31;
        const float m1 = emsc[i * 64 + c];
        const float s1 = fmaxf(emsc[i * 64 + 32 + c], 1e-9f);
        const float m2 = pms[i * 64 + c];
        const float s2 = fmaxf(pms[i * 64 + 32 + c], 1e-9f);
        const float dm = m1 - m2;
        acc += 2.f * (logf(s2) - logf(s1)) + (s1 * s1 + dm * dm) / (s2 * s2) - 1.f;
    }
    for (int off = 32; off > 0; off >>= 1) acc += __shfl_down(acc, off);
    __shared__ float tmp[4];
    if ((threadIdx.x & 63) == 0) tmp[threadIdx.x >> 6] = acc;
    __syncthreads();
    if (threadIdx.x == 0)
        atomicAdd(out + 1, 0.5f * (tmp[0] + tmp[1] + tmp[2] + tmp[3]));
}

// ---------------------------------------------------------------------------
// final: dec_mean2 GEMM + dec_means write + rec/nll reductions. (unchanged)
// ---------------------------------------------------------------------------
__global__ __launch_bounds__(256) void final_kernel(
    const float* __restrict__ ddc,
    const float* __restrict__ W2,
    const float* __restrict__ b2,
    const float* __restrict__ x,
    float* __restrict__ sums,
    float* __restrict__ outDM)
{
    __shared__ float Dh[32][64];
    __shared__ float W2s[64][65];
    const int tid = threadIdx.x;
    const size_t r0 = (size_t)blockIdx.x * 32;

    for (int i = tid; i < 32 * 64; i += 256)
        Dh[i >> 6][i & 63] = ddc[(r0 + (i >> 6)) * 128 + (i & 63)];
    for (int i = tid; i < 64 * 64; i += 256) W2s[i >> 6][i & 63] = W2[i];
    __syncthreads();

    float rec = 0.f, nll = 0.f;
#pragma unroll
    for (int rep = 0; rep < 8; ++rep) {
        const int idx = rep * 256 + tid;
        const int r = idx >> 6, j = idx & 63;
        float acc = b2[j];
#pragma unroll 8
        for (int k = 0; k < 64; ++k) acc += Dh[r][k] * W2s[j][k];
        const size_t g = (r0 + r) * 64 + j;
        const float xv = x[g];
        const float sd = softplus_f(ddc[(r0 + r) * 128 + 64 + j]);
        outDM[g] = acc;
        const float d = xv - acc;
        rec += d * d;
        nll += logf(sd + 1e-5f) + 0.9189385332046727f + d * d / (2.f * sd * sd);
    }
    for (int off = 32; off > 0; off >>= 1) {
        rec += __shfl_down(rec, off);
        nll += __shfl_down(nll, off);
    }
    __shared__ float rr[4], nn[4];
    if ((tid & 63) == 0) { rr[tid >> 6] = rec; nn[tid >> 6] = nll; }
    __syncthreads();
    if (tid == 0) {
        atomicAdd(sums + 0, rr[0] + rr[1] + rr[2] + rr[3]);
        atomicAdd(sums + 2, nn[0] + nn[1] + nn[2] + nn[3]);
    }
}

// ---------------------------------------------------------------------------

static void gemm(hipStream_t s, int M, int N,
                 const bf16* A0, int lda0, const bf16* W0, int ldw0, int K0,
                 const bf16* A1, int lda1, const bf16* W1, int ldw1, int K1,
                 const float* bias, int act, void* C, int ldc, int obf)
{
    dim3 g(N / 64, M / 64), b(256);
    hipLaunchKernelGGL(mfma_gemm, g, b, 0, s,
                       A0, lda0, W0, ldw0, K0, A1, lda1, W1, ldw1, K1,
                       bias, act, C, ldc, obf);
}

static void f2b(hipStream_t s, const float* src, bf16* dst, int n) {
    hipLaunchKernelGGL(f2b_kernel, dim3((n + 255) / 256), dim3(256), 0, s, src, dst, n);
}
static void fcp(hipStream_t s, const float* src, float* dst, int n) {
    hipLaunchKernelGGL(fcopy_kernel, dim3((n + 255) / 256), dim3(256), 0, s, src, dst, n);
}

// bf16-weight element offsets within WB
#define O_PXW1 0
#define O_PXW2 32768
#define O_PZW  294912
#define O_EW1  311296
#define O_EW2  835584
#define O_MSW  1097728
#define O_PRW  1130496
#define O_PMSW 1392640
#define O_DW1  1425408
#define O_DW2  1949696
#define O_DDW  2211840
#define O_GWIH 2277376
#define O_GWHH 3850240
#define WB_ELEMS 4636672ull

// Walk the SAME offset chain as the layout code below (single source of
// truth for the footprint — this mismatch was the R4 crash).
static size_t ws_needed(int tc) {
    size_t off = 27100160ull + (size_t)(tc + 1) * 524288ull;  // ..HLIVE + HH
    off += (size_t)tc * 524288ull;   // R1
    off += (size_t)tc * 524288ull;   // R2
    off += (size_t)tc * 524288ull;   // PHIZC
    off += (size_t)tc * 131072ull;   // EMSC
    off += (size_t)tc * 262144ull;   // U
    off += (size_t)tc * 1572864ull;  // GXX
    return off;
}

extern "C" void kernel_launch(void* const* d_in, const int* in_sizes, int n_in,
                              void* d_out, int out_size, void* d_ws, size_t ws_size,
                              hipStream_t stream)
{
    const float* x_in   = (const float*)d_in[0];
    const float* eps_in = (const float*)d_in[1];
    const float* pxW1 = (const float*)d_in[2];  const float* pxb1 = (const float*)d_in[3];
    const float* pxW2 = (const float*)d_in[4];  const float* pxb2 = (const float*)d_in[5];
    const float* pzW  = (const float*)d_in[6];  const float* pzb  = (const float*)d_in[7];
    const float* eW1  = (const float*)d_in[8];  const float* eb1  = (const float*)d_in[9];
    const float* eW2  = (const float*)d_in[10]; const float* eb2  = (const float*)d_in[11];
    const float* emW  = (const float*)d_in[12]; const float* emb  = (const float*)d_in[13];
    const float* esW  = (const float*)d_in[14]; const float* esb  = (const float*)d_in[15];
    const float* prW  = (const float*)d_in[16]; const float* prb  = (const float*)d_in[17];
    const float* pmW  = (const float*)d_in[18]; const float* pmb  = (const float*)d_in[19];
    const float* psW  = (const float*)d_in[20]; const float* psb  = (const float*)d_in[21];
    const float* dW1  = (const float*)d_in[22]; const float* db1  = (const float*)d_in[23];
    const float* dW2  = (const float*)d_in[24]; const float* db2  = (const float*)d_in[25];
    const float* dsW  = (const float*)d_in[26]; const float* dsb  = (const float*)d_in[27];
    const float* dmW1 = (const float*)d_in[28]; const float* dmb1 = (const float*)d_in[29];
    const float* dmW2 = (const float*)d_in[30]; const float* dmb2 = (const float*)d_in[31];
    const float* gWih = (const float*)d_in[32]; const float* gWhh = (const float*)d_in[33];

    float* out = (float*)d_out;
    char* ws = (char*)d_ws;

    int TC = 1;
    const int cands[9] = {256, 128, 64, 32, 16, 8, 4, 2, 1};
    for (int i = 0; i < 9; ++i)
        if (ws_needed(cands[i]) <= ws_size) { TC = cands[i]; break; }
    const int NCH = 256 / TC;

    // ---- workspace map (all offsets 512B-aligned) ----
    bf16*  WB    = (bf16*)(ws);                         // 9,273,344 B
    float* BB    = (float*)(ws + 9273344ull);           // 1024 B combined biases
    bf16*  XBF   = (bf16*)(ws + 9274368ull);            // 16,777,216 B
    float* HLIVE = (float*)(ws + 26051584ull);          // 1,048,576 B
    bf16*  HH    = (bf16*)(ws + 27100160ull);           // (TC+1)*524,288 B
    size_t off = 27100160ull + (size_t)(TC + 1) * 524288ull;
    bf16*  R1    = (bf16*)(ws + off); off += (size_t)TC * 524288ull;   // also E1X
    bf16*  R2    = (bf16*)(ws + off); off += (size_t)TC * 524288ull;   // PHIX / DECH
    bf16*  PHIZC = (bf16*)(ws + off); off += (size_t)TC * 524288ull;
    float* EMSC  = (float*)(ws + off); off += (size_t)TC * 131072ull;
    float* U     = (float*)(ws + off); off += (size_t)TC * 262144ull;  // PMS then DDC
    bf16*  GXX   = (bf16*)(ws + off);                   // TC*1,572,864 B

    // ---- setup: weight/bias/x conversion ----
    f2b(stream, pxW1, WB + O_PXW1, 32768);
    f2b(stream, pxW2, WB + O_PXW2, 262144);
    f2b(stream, pzW,  WB + O_PZW,  16384);
    f2b(stream, eW1,  WB + O_EW1,  524288);
    f2b(stream, eW2,  WB + O_EW2,  262144);
    f2b(stream, emW,  WB + O_MSW,  16384);
    f2b(stream, esW,  WB + O_MSW + 16384, 16384);
    f2b(stream, prW,  WB + O_PRW,  262144);
    f2b(stream, pmW,  WB + O_PMSW, 16384);
    f2b(stream, psW,  WB + O_PMSW + 16384, 16384);
    f2b(stream, dW1,  WB + O_DW1,  524288);
    f2b(stream, dW2,  WB + O_DW2,  262144);
    f2b(stream, dmW1, WB + O_DDW,  32768);
    f2b(stream, dsW,  WB + O_DDW + 32768, 32768);
    f2b(stream, gWih, WB + O_GWIH, 1572864);
    f2b(stream, gWhh, WB + O_GWHH, 786432);
    f2b(stream, x_in, XBF, 8388608);
    fcp(stream, emb,  BB + 0,   32);
    fcp(stream, esb,  BB + 32,  32);
    fcp(stream, pmb,  BB + 64,  32);
    fcp(stream, psb,  BB + 96,  32);
    fcp(stream, dmb1, BB + 128, 64);
    fcp(stream, dsb,  BB + 192, 64);

    hipLaunchKernelGGL(init_kernel, dim3(1024), dim3(256), 0, stream, HLIVE, out);

    for (int c = 0; c < NCH; ++c) {
        const int cs = c * TC;
        const int MR = TC * 512;

        // ---- pre: phi_x MLP for the chunk ----
        gemm(stream, MR, 512, XBF + (size_t)cs * 32768, 64, WB + O_PXW1, 64, 64,
             nullptr, 0, nullptr, 0, 0, pxb1, 1, R1, 512, 1);
        gemm(stream, MR, 512, R1, 512, WB + O_PXW2, 512, 512,
             nullptr, 0, nullptr, 0, 0, pxb2, 1, R2, 512, 1);

        // ---- pre: hoisted phi_x contributions ----
        // E1X = phi_x @ eW1[:, :512]^T + eb1   (linear, into R1)
        gemm(stream, MR, 512, R2, 512, WB + O_EW1, 1024, 512,
             nullptr, 0, nullptr, 0, 0, eb1, 0, R1, 512, 1);
        // GXX = phi_x @ Wih[:, :512]^T         (no bias)
        gemm(stream, MR, 1536, R2, 512, WB + O_GWIH, 1024, 512,
             nullptr, 0, nullptr, 0, 0, nullptr, 0, GXX, 1536, 1);

        // ---- the entire TC-step recurrence: ONE launch ----
        hipLaunchKernelGGL(seq_kernel, dim3(32), dim3(512), 0, stream,
                           R1, GXX, eps_in + (size_t)cs * 16384,
                           WB + O_EW1 + 512, WB + O_EW2, eb2,
                           WB + O_MSW, BB, WB + O_PZW, pzb,
                           WB + O_GWIH + 512, WB + O_GWHH,
                           HLIVE, HH, EMSC, PHIZC, TC);

        // ---- post: prior + KLD ----
        gemm(stream, MR, 512, HH, 512, WB + O_PRW, 512, 512,
             nullptr, 0, nullptr, 0, 0, prb, 1, R1, 512, 1);
        gemm(stream, MR, 64, R1, 512, WB + O_PMSW, 512, 512,
             nullptr, 0, nullptr, 0, 0, BB + 64, 2, U, 64, 0);
        hipLaunchKernelGGL(kld_kernel, dim3(TC * 16), dim3(256), 0, stream,
                           EMSC, U, out);

        // ---- post: dec + NLL/rec ----
        gemm(stream, MR, 512, PHIZC, 512, WB + O_DW1, 1024, 512,
             HH, 512, WB + O_DW1 + 512, 1024, 512, db1, 1, R1, 512, 1);
        gemm(stream, MR, 512, R1, 512, WB + O_DW2, 512, 512,
             nullptr, 0, nullptr, 0, 0, db2, 1, R2, 512, 1);          // R2: PHIX dead
        gemm(stream, MR, 128, R2, 512, WB + O_DDW, 512, 512,
             nullptr, 0, nullptr, 0, 0, BB + 128, 3, U, 128, 0);
        hipLaunchKernelGGL(final_kernel, dim3(MR / 32), dim3(256), 0, stream,
                           U, dmW2, dmb2, x_in + (size_t)cs * 32768,
                           out, out + 3 + (size_t)cs * 32768);
    }
}